// Round 13
// baseline (1470.891 us; speedup 1.0000x reference)
//
#include <hip/hip_runtime.h>
#include <math.h>

#define TW 64
#define TH 32
#define IMG 1024

#define GSTR 80    // grayb (bf16): 48 rows x 80 cols; b64 lane pattern <=2-way = free
#define ASTR 84    // Abf (bf16): 34 rows x 84 ushort; pair-stride 336B -> bank step 20 -> free
#define SSTR 68    // S (fp32): 34 rows; P3 row-lane reads 2-way = free
#define WCUT 1e-5f // compile-time tap cutoff (dropped mass ~3e-6/pass, negligible)

typedef float v4f __attribute__((ext_vector_type(4)));
typedef float v2f __attribute__((ext_vector_type(2)));

// ---- compile-time Gaussian weights: indexed only with constants -> inline literals.
constexpr double cexp_pos(double t) {
  double term = 1.0, sum = 1.0;
  for (int i = 1; i < 120; ++i) { term *= t / i; sum += term; if (term < 1e-300) break; }
  return sum;
}
constexpr double cexp(double t) { return t < 0 ? 1.0 / cexp_pos(-t) : cexp_pos(t); }

struct WTab {
  float w[189];
  constexpr WTab() : w{} {
    int off = 0;
    for (int ki = 0; ki < 7; ++ki) {
      const int ks = 3 + 2 * ki, r = ks >> 1;
      for (int si = 0; si < 3; ++si) {
        const double s = (double)(1 + si);
        double tmp[15] = {}; double sum = 0.0;
        for (int i = 0; i < ks; ++i) {
          const double x = (double)(i - r);
          tmp[i] = cexp(-x * x / (2.0 * s * s)); sum += tmp[i];
        }
        for (int i = 0; i < ks; ++i) w[off + i] = (float)(tmp[i] / sum);
        off += ks;
      }
    }
  }
};
constexpr WTab WT{};

// bf16 pack/unpack helpers (RNE pack; unpack exact)
__device__ __forceinline__ unsigned f2bf(float f) {
  const unsigned u = __float_as_uint(f);
  return (u + 0x7fffu + ((u >> 16) & 1u)) >> 16;
}
__device__ __forceinline__ unsigned pk2bf(float lo, float hi) {
  return f2bf(lo) | (f2bf(hi) << 16);
}
__device__ __forceinline__ float bflo(unsigned u) { return __uint_as_float(u << 16); }
__device__ __forceinline__ float bfhi(unsigned u) { return __uint_as_float(u & 0xffff0000u); }

// Per-scale processing. R = radius, OFF = offset into WT.w, W = |LoG| multiplicity.
// acc: 8 VGPR-resident floats (demand ~60 vs (256,3) cap ~85 -> no spill expected;
// R3/R6/R7 spills were at-cap allocations from a fat fp32 baseline).
template<int R, int OFF, int W>
__device__ __forceinline__ void do_scale(
    const unsigned short* __restrict__ grayb, unsigned short* __restrict__ Abf,
    float* __restrict__ S, float* __restrict__ acc, int tid, int x0, int y0)
{
  // ---- P1: vertical blur grayb -> Abf. v4f accumulate -> v_pk_fma_f32 pairs.
  if (tid < 180) {
    const int q   = tid % 20;
    const int seg = tid / 20;
    const int ys  = seg * 4;
    const bool full = (seg < 8);             // seg 8 computes only rows 32,33
    v4f a4[4];
#pragma unroll
    for (int gi = 0; gi < 4; ++gi) a4[gi] = (v4f){0.f, 0.f, 0.f, 0.f};
#pragma unroll
    for (int kk = 0; kk < 4 + 2*R; ++kk) {
      const bool kok = (kk < 2 + 2*R);
      if (full || kok) {
        const uint2 g2 = *(const uint2*)&grayb[(ys + 7 - R + kk)*GSTR + 4*q];
        const v4f v = (v4f){bflo(g2.x), bfhi(g2.x), bflo(g2.y), bfhi(g2.y)};
#pragma unroll
        for (int gi = 0; gi < 4; ++gi) {
          const int d = kk - gi;             // tap index 0..2R (compile-time)
          if (d >= 0 && d <= 2*R) {
            if (WT.w[OFF + d] >= WCUT) {     // compile-time tap skip
              if (gi < 2 || full) {
                const float wt = WT.w[OFF + d];
                const v4f w4 = (v4f){wt, wt, wt, wt};
                a4[gi] = __builtin_elementwise_fma(w4, v, a4[gi]);
              }
            }
          }
        }
      }
    }
#pragma unroll
    for (int gi = 0; gi < 4; ++gi)
      if (gi < 2 || full) {
        uint2 pk;
        pk.x = pk2bf(a4[gi].x, a4[gi].y);
        pk.y = pk2bf(a4[gi].z, a4[gi].w);
        *(uint2*)&Abf[(ys + gi)*ASTR + 4*q] = pk;
      }
  }
  __syncthreads();

  // ---- P2: horizontal blur Abf -> S, ROW-PAIR vectorized (v2f lanes = 2 rows).
  // 153 items = 17 row-pairs x 9 col-groups, one per thread (tid<153).
  if (tid < 153) {
    constexpr int Q0   = (7 - R) >> 2;
    constexpr int NQ   = ((14 + R) >> 2) - Q0 + 1;
    constexpr int BASE = 7 - R - 4*Q0;
    const int pr = tid % 17, cg = tid / 17;
    const int rA = 2*pr, rB = 2*pr + 1;
    v2f av2[4*NQ];
#pragma unroll
    for (int i = 0; i < NQ; ++i) {
      const uint2 ga = *(const uint2*)&Abf[rA*ASTR + 8*cg + 4*(Q0 + i)];
      const uint2 gb = *(const uint2*)&Abf[rB*ASTR + 8*cg + 4*(Q0 + i)];
      av2[4*i]     = (v2f){bflo(ga.x), bflo(gb.x)};
      av2[4*i + 1] = (v2f){bfhi(ga.x), bfhi(gb.x)};
      av2[4*i + 2] = (v2f){bflo(ga.y), bflo(gb.y)};
      av2[4*i + 3] = (v2f){bfhi(ga.y), bfhi(gb.y)};
    }
    v2f s2[8];
#pragma unroll
    for (int o = 0; o < 8; ++o) s2[o] = (v2f){0.f, 0.f};
#pragma unroll
    for (int t = 0; t <= 2*R; ++t) {
      if (WT.w[OFF + t] >= WCUT) {                     // compile-time tap skip
        const float wt = WT.w[OFF + t];
        const v2f w2 = (v2f){wt, wt};
#pragma unroll
        for (int o = 0; o < 8; ++o)
          s2[o] = __builtin_elementwise_fma(w2, av2[o + BASE + t], s2[o]);
      }
    }
    const int gyA = y0 - 1 + rA, gyB = y0 - 1 + rB;
    const int gx0 = x0 - 1 + 8*cg;
    const bool okA = ((unsigned)gyA < (unsigned)IMG);
    const bool okB = ((unsigned)gyB < (unsigned)IMG);
    float oA[8], oB[8];
#pragma unroll
    for (int o = 0; o < 8; ++o) {
      const bool cok = ((unsigned)(gx0 + o) < (unsigned)IMG);
      // Laplacian input is smooth zero-padded by 1: outside-image slots are 0.
      oA[o] = (okA && cok) ? s2[o].x : 0.f;
      oB[o] = (okB && cok) ? s2[o].y : 0.f;
    }
    if (cg < 8) {
      *(float4*)&S[rA*SSTR + 8*cg]     = make_float4(oA[0], oA[1], oA[2], oA[3]);
      *(float4*)&S[rA*SSTR + 8*cg + 4] = make_float4(oA[4], oA[5], oA[6], oA[7]);
      *(float4*)&S[rB*SSTR + 8*cg]     = make_float4(oB[0], oB[1], oB[2], oB[3]);
      *(float4*)&S[rB*SSTR + 8*cg + 4] = make_float4(oB[4], oB[5], oB[6], oB[7]);
    } else {
      S[rA*SSTR + 64] = oA[0];
      S[rA*SSTR + 65] = oA[1];
      S[rB*SSTR + 64] = oB[0];
      S[rB*SSTR + 65] = oB[1];
    }
  }
  __syncthreads();

  // ---- P3: 5-point Laplacian of S; acc += W * |log| (VGPR accumulate).
  // row = tid&31: consecutive lanes step rows (bank step 4) -> conflict-free.
  {
    const int row = tid & 31, cg = tid >> 5;
    float T[12], M[12], B[12];
#pragma unroll
    for (int i = 0; i < 3; ++i) {
      *(float4*)&T[4*i] = *(const float4*)&S[(row    )*SSTR + 8*cg + 4*i];
      *(float4*)&M[4*i] = *(const float4*)&S[(row + 1)*SSTR + 8*cg + 4*i];
      *(float4*)&B[4*i] = *(const float4*)&S[(row + 2)*SSTR + 8*cg + 4*i];
    }
    const float wm = (float)W;   // 1.0/2.0/4.0 are free inline constants
#pragma unroll
    for (int o = 0; o < 8; ++o) {
      const int j = o + 1;
      const float lg = T[j] + B[j] + M[j-1] + M[j+1] - 4.f*M[j];
      acc[o] += wm * fabsf(lg);
    }
  }
  // NO barrier here: next P1 writes Abf (disjoint from S); the post-P1 barrier
  // orders this P3's S-reads against the next P2's S-writes. acc is per-thread.
}

__global__ __launch_bounds__(256, 3)
void MultiscaleLoG_kernel(const float* __restrict__ in, float* __restrict__ out)
{
  // Declaration order matters: Abf's <=16B read-overshoot (cg=8 dead lanes, R=7,
  // last row) must land in S, not past the LDS block.
  __shared__ __align__(16) unsigned short grayb[48*GSTR]; //  7680 B (bf16)
  __shared__ __align__(16) unsigned short Abf[34*ASTR];   //  5712 B (bf16)
  __shared__ __align__(16) float S[34*SSTR];              //  9248 B
  // total 22640 B -> 23040 granule -> 7 blocks/CU (28 waves, 87.5%)

  const int tid = threadIdx.x;
  const int x0 = blockIdx.x * TW;
  const int y0 = blockIdx.y * TH;
  const int b  = blockIdx.z;
  const float* __restrict__ base = in + (size_t)b * 3u * 1048576u;

  // ---- stage gray = channel mean with halo (rows y0-8..y0+39, cols x0-8..x0+71),
  //      rounded to bf16 (RNE); zero outside image.
  const bool interior = (x0 >= 8) & (x0 + 72 <= IMG) & (y0 >= 8) & (y0 + 40 <= IMG);
#pragma unroll 1
  for (int u = tid; u < 960; u += 256) {          // 20 quads x 48 rows
    const int q = u % 20, gr = u / 20;
    const int gx = x0 - 8 + 4*q, gy = y0 - 8 + gr;
    v4f v;
    if (interior) {
      const float* p = base + (size_t)gy * IMG + gx;
      const v4f c0 = *(const v4f*)p;
      const v4f c1 = *(const v4f*)(p + 1048576);
      const v4f c2 = *(const v4f*)(p + 2097152);
      v = (c0 + c1 + c2) * (1.f/3.f);
    } else {
      float t4[4];
#pragma unroll
      for (int j = 0; j < 4; ++j) {
        const int xx = gx + j;
        float s = 0.f;
        if ((unsigned)xx < (unsigned)IMG && (unsigned)gy < (unsigned)IMG) {
          const float* p = base + (size_t)gy * IMG + xx;
          s = (p[0] + p[1048576] + p[2097152]) * (1.f/3.f);
        }
        t4[j] = s;
      }
      v = (v4f){t4[0], t4[1], t4[2], t4[3]};
    }
    uint2 pk;
    pk.x = pk2bf(v.x, v.y);
    pk.y = pk2bf(v.z, v.w);
    *(uint2*)&grayb[gr*GSTR + 4*q] = pk;
  }
  __syncthreads();

  float acc[8];
#pragma unroll
  for (int i = 0; i < 8; ++i) acc[i] = 0.f;

  // ---- 17 passes covering the 21 reference scales (merged duplicates:
  //  sigma=1 ks9/11/13/15 -> W=4 at ks9; sigma=2 ks13/15 -> W=2 at ks15).
#define DS(R, OFF, W) do_scale<R, OFF, W>(grayb, Abf, S, acc, tid, x0, y0);
  DS(1, 0,   1)   // ks3  s1
  DS(1, 3,   1)   // ks3  s2
  DS(1, 6,   1)   // ks3  s3
  DS(2, 9,   1)   // ks5  s1
  DS(2, 14,  1)   // ks5  s2
  DS(2, 19,  1)   // ks5  s3
  DS(3, 24,  1)   // ks7  s1
  DS(3, 31,  1)   // ks7  s2
  DS(3, 38,  1)   // ks7  s3
  DS(4, 45,  4)   // ks9  s1  == ks9+ks11+ks13+ks15 at s1
  DS(4, 54,  1)   // ks9  s2
  DS(4, 63,  1)   // ks9  s3
  DS(5, 83,  1)   // ks11 s2
  DS(5, 94,  1)   // ks11 s3
  DS(7, 159, 2)   // ks15 s2  == ks13+ks15 at s2
  DS(6, 131, 1)   // ks13 s3
  DS(7, 174, 1)   // ks15 s3
#undef DS

  // ---- coalesced output via LDS transpose through S (acc ownership row=tid&31)
  __syncthreads();                         // all P3 S-reads done before overwrite
  {
    const int row = tid & 31, cg = tid >> 5;
    *(float4*)&S[row*SSTR + 8*cg]     = make_float4(acc[0], acc[1], acc[2], acc[3]);
    *(float4*)&S[row*SSTR + 8*cg + 4] = make_float4(acc[4], acc[5], acc[6], acc[7]);
  }
  __syncthreads();
  {
    const int cg = tid & 7, row = tid >> 3;
    const float4 lo = *(const float4*)&S[row*SSTR + 8*cg];
    const float4 hi = *(const float4*)&S[row*SSTR + 8*cg + 4];
    float* op = out + ((size_t)b * IMG + (y0 + row)) * IMG + x0 + 8*cg;
    *(float4*)&op[0] = lo;
    *(float4*)&op[4] = hi;
  }
}

extern "C" void kernel_launch(void* const* d_in, const int* in_sizes, int n_in,
                              void* d_out, int out_size, void* d_ws, size_t ws_size,
                              hipStream_t stream) {
  (void)in_sizes; (void)n_in; (void)d_ws; (void)ws_size; (void)out_size;
  const float* in = (const float*)d_in[0];
  float* out = (float*)d_out;
  dim3 grid(IMG / TW, IMG / TH, 16);
  MultiscaleLoG_kernel<<<grid, dim3(256), 0, stream>>>(in, out);
}